// Round 1
// baseline (201.569 us; speedup 1.0000x reference)
//
#include <hip/hip_runtime.h>
#include <hip/hip_bf16.h>

#define B_ 4096
#define L_ 50
#define D_ 64

__device__ __forceinline__ float sigmoidf_(float x) { return 1.0f / (1.0f + expf(-x)); }

__device__ __forceinline__ float seluf_(float x) {
    const float sc = 1.0507009873554805f, al = 1.6732632423543772f;
    return x > 0.0f ? sc * x : sc * al * expm1f(x);
}

// ---------------------------------------------------------------------------
// k1: per-b fused gather + gate + fusion + double-l2norm + sum over L.
// att_history[b][d] = 0.5*(sum_l v + sum_l v2), v = l2norm(o), v2 = l2norm(v)
// Layout: 4 waves; each wave processes 4 rows (l) at a time, 16 lanes per row,
// each lane computes 4 output dims (d = 4g..4g+3).
// ---------------------------------------------------------------------------
__global__ __launch_bounds__(256) void k1_fuse(
    const int* __restrict__ hist_ui, const int* __restrict__ hist_r,
    const float* __restrict__ i2e, const float* __restrict__ r2e,
    const float* __restrict__ gate_w, const float* __restrict__ gate_b,
    float* __restrict__ ws_att)
{
    __shared__ float sW[192 * 64];       // gate_w staged, 48 KB
    __shared__ float sX[16][200];        // x3 rows, padded to 200 (bank-conflict-free)
    __shared__ float sRed[2][4][64];     // per-wave partials (f1, f2)

    const int b   = blockIdx.x;
    const int tid = threadIdx.x;
    const int wv  = tid >> 6;            // wave 0..3
    const int ln  = tid & 63;
    const int rg  = ln >> 4;             // row subgroup 0..3
    const int g   = ln & 15;             // output group: d = 4g..4g+3

    {
        const float4* src = reinterpret_cast<const float4*>(gate_w);
        float4* dst = reinterpret_cast<float4*>(sW);
        #pragma unroll
        for (int i = 0; i < 12; ++i) dst[tid + 256 * i] = src[tid + 256 * i];
    }
    const float4 gb = reinterpret_cast<const float4*>(gate_b)[g];
    __syncthreads();

    float f1x = 0, f1y = 0, f1z = 0, f1w = 0;
    float f2x = 0, f2y = 0, f2z = 0, f2w = 0;

    float* xr = sX[wv * 4 + rg];
    float4* xr4 = reinterpret_cast<float4*>(xr);
    const float4* w4 = reinterpret_cast<const float4*>(sW);

    for (int it = 0; it < 4; ++it) {
        const int l = it * 16 + wv * 4 + rg;
        float4 eui = make_float4(0.f, 0.f, 0.f, 0.f);
        float4 er  = make_float4(0.f, 0.f, 0.f, 0.f);
        if (l < L_) {
            const int iu = hist_ui[b * L_ + l];
            const int ir = hist_r[b * L_ + l];
            eui = reinterpret_cast<const float4*>(i2e + (size_t)iu * D_)[g];
            er  = reinterpret_cast<const float4*>(r2e + (size_t)ir * D_)[g];
        }
        // x3 = [e_ui | e_r | e_ui*e_r]
        xr4[g]      = eui;
        xr4[16 + g] = er;
        xr4[32 + g] = make_float4(eui.x * er.x, eui.y * er.y, eui.z * er.z, eui.w * er.w);
        __builtin_amdgcn_wave_barrier();   // wave-internal LDS write->read ordering

        float a0 = gb.x, a1 = gb.y, a2 = gb.z, a3 = gb.w;
        #pragma unroll 8
        for (int k = 0; k < 192; ++k) {
            const float xv = xr[k];
            const float4 w = w4[k * 16 + g];
            a0 = fmaf(xv, w.x, a0);
            a1 = fmaf(xv, w.y, a1);
            a2 = fmaf(xv, w.z, a2);
            a3 = fmaf(xv, w.w, a3);
        }
        a0 = sigmoidf_(a0); a1 = sigmoidf_(a1); a2 = sigmoidf_(a2); a3 = sigmoidf_(a3);
        const float o0 = a0 * eui.x + (1.0f - a0) * er.x;
        const float o1 = a1 * eui.y + (1.0f - a1) * er.y;
        const float o2 = a2 * eui.z + (1.0f - a2) * er.z;
        const float o3 = a3 * eui.w + (1.0f - a3) * er.w;

        float s = o0 * o0 + o1 * o1 + o2 * o2 + o3 * o3;
        s += __shfl_xor(s, 1); s += __shfl_xor(s, 2);
        s += __shfl_xor(s, 4); s += __shfl_xor(s, 8);
        const float m = fmaxf(sqrtf(s), 1e-12f);
        const float v0 = o0 / m, v1 = o1 / m, v2 = o2 / m, v3 = o3 / m;

        float s2 = v0 * v0 + v1 * v1 + v2 * v2 + v3 * v3;
        s2 += __shfl_xor(s2, 1); s2 += __shfl_xor(s2, 2);
        s2 += __shfl_xor(s2, 4); s2 += __shfl_xor(s2, 8);
        const float m2 = fmaxf(sqrtf(s2), 1e-12f);

        f1x += v0; f1y += v1; f1z += v2; f1w += v3;
        f2x += v0 / m2; f2y += v1 / m2; f2z += v2 / m2; f2w += v3 / m2;
        __builtin_amdgcn_wave_barrier();   // keep next iter's writes after reads
    }

    // reduce across the 4 row subgroups (lanes differing in bits 16,32)
    f1x += __shfl_xor(f1x, 16); f1x += __shfl_xor(f1x, 32);
    f1y += __shfl_xor(f1y, 16); f1y += __shfl_xor(f1y, 32);
    f1z += __shfl_xor(f1z, 16); f1z += __shfl_xor(f1z, 32);
    f1w += __shfl_xor(f1w, 16); f1w += __shfl_xor(f1w, 32);
    f2x += __shfl_xor(f2x, 16); f2x += __shfl_xor(f2x, 32);
    f2y += __shfl_xor(f2y, 16); f2y += __shfl_xor(f2y, 32);
    f2z += __shfl_xor(f2z, 16); f2z += __shfl_xor(f2z, 32);
    f2w += __shfl_xor(f2w, 16); f2w += __shfl_xor(f2w, 32);

    if (rg == 0) {
        sRed[0][wv][4 * g + 0] = f1x; sRed[0][wv][4 * g + 1] = f1y;
        sRed[0][wv][4 * g + 2] = f1z; sRed[0][wv][4 * g + 3] = f1w;
        sRed[1][wv][4 * g + 0] = f2x; sRed[1][wv][4 * g + 1] = f2y;
        sRed[1][wv][4 * g + 2] = f2z; sRed[1][wv][4 * g + 3] = f2w;
    }
    __syncthreads();
    if (tid < 64) {
        float t = 0.f;
        #pragma unroll
        for (int w = 0; w < 4; ++w) t += sRed[0][w][tid] + sRed[1][w][tid];
        ws_att[(size_t)b * D_ + tid] = 0.5f * t;
    }
}

// ---------------------------------------------------------------------------
// Deterministic per-column batch stats: mean + 1/sqrt(var+eps). One block per d.
// ---------------------------------------------------------------------------
__global__ __launch_bounds__(256) void k_stats(
    const float* __restrict__ x, float* __restrict__ mean_istd)
{
    const int d = blockIdx.x;
    const int tid = threadIdx.x;
    float s = 0.f, ss = 0.f;
    for (int b = tid; b < B_; b += 256) {
        const float v = x[(size_t)b * D_ + d];
        s += v; ss += v * v;
    }
    __shared__ float rs[256], rss[256];
    rs[tid] = s; rss[tid] = ss;
    __syncthreads();
    for (int o = 128; o > 0; o >>= 1) {
        if (tid < o) { rs[tid] += rs[tid + o]; rss[tid] += rss[tid + o]; }
        __syncthreads();
    }
    if (tid == 0) {
        const float m = rs[0] * (1.0f / B_);
        const float var = rss[0] * (1.0f / B_) - m * m;
        mean_istd[d] = m;
        mean_istd[64 + d] = rsqrtf(fmaxf(var, 0.0f) + 1e-5f);
    }
}

// ---------------------------------------------------------------------------
// h1 = selu( bn(att) @ inproj_w + inproj_b ). One row per wave.
// ---------------------------------------------------------------------------
__global__ __launch_bounds__(256) void k_inproj(
    const float* __restrict__ att, const float* __restrict__ st,
    const float* __restrict__ bn_g, const float* __restrict__ bn_b,
    const float* __restrict__ W, const float* __restrict__ bias,
    float* __restrict__ h1)
{
    __shared__ float sW[64 * 64];
    __shared__ float sx[4][64];
    const int tid = threadIdx.x, wv = tid >> 6, ln = tid & 63;
    #pragma unroll
    for (int i = 0; i < 16; ++i) sW[tid + 256 * i] = W[tid + 256 * i];
    __syncthreads();

    const int b = blockIdx.x * 4 + wv;
    const float xn = (att[(size_t)b * D_ + ln] - st[ln]) * st[64 + ln] * bn_g[ln] + bn_b[ln];
    sx[wv][ln] = xn;
    __builtin_amdgcn_wave_barrier();
    float acc = bias[ln];
    #pragma unroll 8
    for (int k = 0; k < 64; ++k) acc = fmaf(sx[wv][k], sW[k * 64 + ln], acc);
    h1[(size_t)b * D_ + ln] = seluf_(acc);
}

// ---------------------------------------------------------------------------
// n = bn1(h1) @ outproj + b; self = u2e[nodes]; beta = sigmoid([self|n|self*n]@gate1);
// out = beta*self + (1-beta)*n. One row per wave.
// ---------------------------------------------------------------------------
__global__ __launch_bounds__(256) void k_final(
    const float* __restrict__ h1, const float* __restrict__ st,
    const float* __restrict__ bn1_g, const float* __restrict__ bn1_b,
    const float* __restrict__ Wout, const float* __restrict__ bout,
    const int* __restrict__ nodes, const float* __restrict__ u2e,
    const float* __restrict__ g1w, const float* __restrict__ g1b,
    float* __restrict__ out)
{
    __shared__ float sWo[64 * 64];     // 16 KB
    __shared__ float sG[192 * 64];     // 48 KB
    __shared__ float sx[4][64];
    __shared__ float sc[4][192];
    const int tid = threadIdx.x, wv = tid >> 6, ln = tid & 63;
    #pragma unroll
    for (int i = 0; i < 16; ++i) sWo[tid + 256 * i] = Wout[tid + 256 * i];
    #pragma unroll
    for (int i = 0; i < 48; ++i) sG[tid + 256 * i] = g1w[tid + 256 * i];
    __syncthreads();

    const int b = blockIdx.x * 4 + wv;
    const float xn = (h1[(size_t)b * D_ + ln] - st[ln]) * st[64 + ln] * bn1_g[ln] + bn1_b[ln];
    sx[wv][ln] = xn;
    __builtin_amdgcn_wave_barrier();
    float acc = bout[ln];
    #pragma unroll 8
    for (int k = 0; k < 64; ++k) acc = fmaf(sx[wv][k], sWo[k * 64 + ln], acc);
    const float nn = acc;
    const float self = u2e[(size_t)nodes[b] * D_ + ln];

    sc[wv][ln] = self;
    sc[wv][64 + ln] = nn;
    sc[wv][128 + ln] = self * nn;
    __builtin_amdgcn_wave_barrier();
    float bacc = g1b[ln];
    #pragma unroll 8
    for (int k = 0; k < 192; ++k) bacc = fmaf(sc[wv][k], sG[k * 64 + ln], bacc);
    const float beta = sigmoidf_(bacc);
    out[(size_t)b * D_ + ln] = beta * self + (1.0f - beta) * nn;
}

extern "C" void kernel_launch(void* const* d_in, const int* in_sizes, int n_in,
                              void* d_out, int out_size, void* d_ws, size_t ws_size,
                              hipStream_t stream) {
    (void)in_sizes; (void)n_in; (void)out_size; (void)ws_size;
    const int*   nodes     = (const int*)d_in[0];
    const int*   hist_ui   = (const int*)d_in[1];
    const int*   hist_r    = (const int*)d_in[2];
    const float* i2e_w     = (const float*)d_in[3];
    const float* u2e_w     = (const float*)d_in[4];
    const float* r2e_w     = (const float*)d_in[5];
    // d_in[6..13]: att1/att2/att3/lin1 weights+biases -- dead code (entmax over
    // a size-1 axis is identically 1.0, so att == 1 and the score MLP is unused).
    const float* gate_w    = (const float*)d_in[14];
    const float* gate_b    = (const float*)d_in[15];
    const float* gate1_w   = (const float*)d_in[16];
    const float* gate1_b   = (const float*)d_in[17];
    const float* bn_g      = (const float*)d_in[18];
    const float* bn_b      = (const float*)d_in[19];
    const float* inproj_w  = (const float*)d_in[20];
    const float* inproj_b  = (const float*)d_in[21];
    const float* bn1_g     = (const float*)d_in[22];
    const float* bn1_b     = (const float*)d_in[23];
    const float* outproj_w = (const float*)d_in[24];
    const float* outproj_b = (const float*)d_in[25];

    float* out    = (float*)d_out;
    float* ws     = (float*)d_ws;
    float* ws_att = ws;                    // B*D floats
    float* ws_h1  = ws + (size_t)B_ * D_;  // B*D floats
    float* st0    = ws + (size_t)2 * B_ * D_;  // 128 floats: mean | istd
    float* st1    = st0 + 128;                 // 128 floats

    k1_fuse<<<B_, 256, 0, stream>>>(hist_ui, hist_r, i2e_w, r2e_w, gate_w, gate_b, ws_att);
    k_stats<<<64, 256, 0, stream>>>(ws_att, st0);
    k_inproj<<<B_ / 4, 256, 0, stream>>>(ws_att, st0, bn_g, bn_b, inproj_w, inproj_b, ws_h1);
    k_stats<<<64, 256, 0, stream>>>(ws_h1, st1);
    k_final<<<B_ / 4, 256, 0, stream>>>(ws_h1, st1, bn1_g, bn1_b, outproj_w, outproj_b,
                                        nodes, u2e_w, gate1_w, gate1_b, out);
}

// Round 2
// 82.877 us; speedup vs baseline: 2.4322x; 2.4322x over previous
//
#include <hip/hip_runtime.h>
#include <hip/hip_bf16.h>

#define B_ 4096
#define L_ 50
#define D_ 64

typedef __attribute__((ext_vector_type(8))) short short8;
typedef __attribute__((ext_vector_type(4))) float f32x4;

__device__ __forceinline__ float sigmoidf_(float x) { return 1.0f / (1.0f + expf(-x)); }

__device__ __forceinline__ float seluf_(float x) {
    const float sc = 1.0507009873554805f, al = 1.6732632423543772f;
    return x > 0.0f ? sc * x : sc * al * expm1f(x);
}

__device__ __forceinline__ unsigned short bf16_(float f) {
    union { float f; unsigned u; } c; c.f = f;
    unsigned u = c.u + 0x7fff + ((c.u >> 16) & 1);   // RNE
    return (unsigned short)(u >> 16);
}

// ---------------------------------------------------------------------------
// pk_w: build A-operand fragments: A = W''^T, W'' = [gate_w rows 0..63 (W1);
// rows 128..191 (W3)], K=128. Fragment (rb,s): lane l holds
// A[dim=16rb+(l&15)][k=32s+8*(l>>4)+j], j=0..7, as bf16. 1024 threads.
// ---------------------------------------------------------------------------
__global__ __launch_bounds__(256) void pk_w(const float* __restrict__ gate_w,
                                            unsigned short* __restrict__ wfrag) {
    const int t = blockIdx.x * 256 + threadIdx.x;   // 0..1023
    const int rb = t >> 8, s = (t >> 6) & 3, l = t & 63;
    const int dim = 16 * rb + (l & 15);
    short8 o;
    #pragma unroll
    for (int j = 0; j < 8; ++j) {
        int k = 32 * s + 8 * (l >> 4) + j;          // 0..127
        int row = k + (k >= 64 ? 64 : 0);           // W1: 0..63, W3: 128..191
        o[j] = (short)bf16_(gate_w[row * 64 + dim]);
    }
    reinterpret_cast<short8*>(wfrag)[t] = o;
}

// ---------------------------------------------------------------------------
// pk_c: c[r][dim] = gate_b[dim] + sum_k r2e[r][k]*W2[k][dim]; slot r=5 is zero
// (pad rows). One block, 384 threads.
// ---------------------------------------------------------------------------
__global__ __launch_bounds__(384) void pk_c(const float* __restrict__ r2e,
                                            const float* __restrict__ gate_w,
                                            const float* __restrict__ gate_b,
                                            float* __restrict__ cbuf) {
    const int t = threadIdx.x;                      // 0..383
    const int r = t >> 6, dim = t & 63;
    float acc = 0.0f;
    if (r < 5) {
        acc = gate_b[dim];
        for (int k = 0; k < 64; ++k)
            acc = fmaf(r2e[r * 64 + k], gate_w[(64 + k) * 64 + dim], acc);
    }
    cbuf[t] = acc;
}

// ---------------------------------------------------------------------------
// k1: per-b fused gather + bf16-MFMA gate + fusion + l2norm + sum over L.
// ws_att[b][d] = sum_l l2norm(a*e_ui + (1-a)*e_r)[d],  a = sigmoid(x3@W+b).
// 4 waves; wave wv owns batch-rows 16wv..16wv+15 (rows >= 50 padded zero).
// C = A*B with A = W''^T frags (LDS), B = [e_ui|e_ui*e_r]^T frags (LDS).
// C layout: col = lane&15 = batch-row, row = dim = 16rb + 4*(l>>4) + q.
// ---------------------------------------------------------------------------
__global__ __launch_bounds__(256) void k1_fuse(
    const int* __restrict__ hist_ui, const int* __restrict__ hist_r,
    const float* __restrict__ i2e,
    const unsigned short* __restrict__ wfrag, const float* __restrict__ cbuf,
    const float* __restrict__ r2e,
    float* __restrict__ ws_att)
{
    __shared__ short8 sWA[16 * 64];                 // [rb*4+s][l]  16 KB
    __shared__ short8 sXB[16 * 64];                 // [wv*4+s][l]  16 KB
    __shared__ __align__(16) float sR2E[6 * 64];    // rating table, slot5 = 0
    __shared__ __align__(16) float sC[6 * 64];      // c_r table,   slot5 = 0
    __shared__ int sIdx[64], sRr[64];
    __shared__ __align__(16) float sRed[4][64];

    const int b   = blockIdx.x;
    const int tid = threadIdx.x;
    const int wv  = tid >> 6;
    const int l   = tid & 63;
    const int h   = l >> 4;       // k-oct group / dim-quad selector
    const int c16 = l & 15;

    // ---- stage ----
    #pragma unroll
    for (int i = 0; i < 4; ++i)
        sWA[tid + 256 * i] = reinterpret_cast<const short8*>(wfrag)[tid + 256 * i];
    for (int i = tid; i < 384; i += 256) {
        sR2E[i] = (i < 320) ? r2e[i] : 0.0f;
        sC[i]   = cbuf[i];
    }
    if (tid < 64) {
        sIdx[tid] = (tid < L_) ? hist_ui[b * L_ + tid] : 0;
        sRr[tid]  = (tid < L_) ? hist_r[b * L_ + tid]  : 5;
    }
    __syncthreads();

    // ---- gather + pack B fragments (each wave packs its own 16 rows) ----
    #pragma unroll
    for (int it = 0; it < 4; ++it) {
        const int r15 = it * 4 + h;                 // row within wave 0..15
        const int br  = wv * 16 + r15;
        const bool valid = br < L_;
        const int rr = sRr[br];
        float4 eui = make_float4(0.f, 0.f, 0.f, 0.f);
        if (valid)
            eui = reinterpret_cast<const float4*>(i2e + (size_t)sIdx[br] * D_)[c16];
        const float4 er = reinterpret_cast<const float4*>(sR2E + rr * 64)[c16];
        const float4 pr = make_float4(eui.x * er.x, eui.y * er.y,
                                      eui.z * er.z, eui.w * er.w);
        const ushort4 be = make_ushort4(bf16_(eui.x), bf16_(eui.y), bf16_(eui.z), bf16_(eui.w));
        const ushort4 bp = make_ushort4(bf16_(pr.x),  bf16_(pr.y),  bf16_(pr.z),  bf16_(pr.w));
        const int o0 = c16 >> 1;                    // eui oct 0..7  (k 0..63)
        const int o1 = 8 + (c16 >> 1);              // prod oct 8..15 (k 64..127)
        const int slot0 = (o0 >> 2) * 64 + r15 + 16 * (o0 & 3);
        const int slot1 = (o1 >> 2) * 64 + r15 + 16 * (o1 & 3);
        char* base = (char*)(sXB + wv * 256);
        *reinterpret_cast<ushort4*>(base + slot0 * 16 + (c16 & 1) * 8) = be;
        *reinterpret_cast<ushort4*>(base + slot1 * 16 + (c16 & 1) * 8) = bp;
    }
    __syncthreads();

    // ---- MFMA: 16 per wave ----
    f32x4 acc[4];
    #pragma unroll
    for (int rb = 0; rb < 4; ++rb) acc[rb] = (f32x4){0.f, 0.f, 0.f, 0.f};
    #pragma unroll
    for (int s = 0; s < 4; ++s) {
        const short8 bfrag = sXB[wv * 256 + s * 64 + l];
        #pragma unroll
        for (int rb = 0; rb < 4; ++rb)
            acc[rb] = __builtin_amdgcn_mfma_f32_16x16x32_bf16(
                sWA[(rb * 4 + s) * 64 + l], bfrag, acc[rb], 0, 0, 0);
    }

    // ---- epilogue: logit -> sigmoid -> fuse -> l2norm -> sum over rows ----
    const int br = wv * 16 + c16;                   // this lane's batch-row
    const float vm = (br < L_) ? 1.0f : 0.0f;
    const int rr = sRr[br];
    const float4* euibase = reinterpret_cast<const float4*>(i2e + (size_t)sIdx[br] * D_);
    float o[4][4];
    float ssq = 0.0f;
    #pragma unroll
    for (int rb = 0; rb < 4; ++rb) {
        const int fq = 4 * rb + h;                  // float4 index: dims 16rb+4h..+3
        const float4 cc  = reinterpret_cast<const float4*>(sC)[rr * 16 + fq];
        const float4 er4 = reinterpret_cast<const float4*>(sR2E)[rr * 16 + fq];
        const float4 eu4 = euibase[fq];
        #pragma unroll
        for (int q = 0; q < 4; ++q) {
            const float lg = acc[rb][q] + (&cc.x)[q];
            const float a  = sigmoidf_(lg);
            const float ov = (a * (&eu4.x)[q] + (1.0f - a) * (&er4.x)[q]) * vm;
            o[rb][q] = ov;
            ssq = fmaf(ov, ov, ssq);
        }
    }
    ssq += __shfl_xor(ssq, 16);
    ssq += __shfl_xor(ssq, 32);
    const float inv = 1.0f / fmaxf(sqrtf(ssq), 1e-12f);
    #pragma unroll
    for (int rb = 0; rb < 4; ++rb)
        #pragma unroll
        for (int q = 0; q < 4; ++q) {
            float v = o[rb][q] * inv;
            v += __shfl_xor(v, 1); v += __shfl_xor(v, 2);
            v += __shfl_xor(v, 4); v += __shfl_xor(v, 8);
            o[rb][q] = v;                           // sum over the wave's 16 rows
        }
    if (c16 == 0) {
        #pragma unroll
        for (int rb = 0; rb < 4; ++rb)
            reinterpret_cast<float4*>(sRed[wv])[4 * rb + h] =
                make_float4(o[rb][0], o[rb][1], o[rb][2], o[rb][3]);
    }
    __syncthreads();
    if (tid < 64)
        ws_att[(size_t)b * D_ + tid] =
            sRed[0][tid] + sRed[1][tid] + sRed[2][tid] + sRed[3][tid];
}

// ---------------------------------------------------------------------------
// Deterministic per-column batch stats: mean + 1/sqrt(var+eps). One block per d.
// ---------------------------------------------------------------------------
__global__ __launch_bounds__(256) void k_stats(
    const float* __restrict__ x, float* __restrict__ mean_istd)
{
    const int d = blockIdx.x;
    const int tid = threadIdx.x;
    float s = 0.f, ss = 0.f;
    for (int b = tid; b < B_; b += 256) {
        const float v = x[(size_t)b * D_ + d];
        s += v; ss += v * v;
    }
    __shared__ float rs[256], rss[256];
    rs[tid] = s; rss[tid] = ss;
    __syncthreads();
    for (int o = 128; o > 0; o >>= 1) {
        if (tid < o) { rs[tid] += rs[tid + o]; rss[tid] += rss[tid + o]; }
        __syncthreads();
    }
    if (tid == 0) {
        const float m = rs[0] * (1.0f / B_);
        const float var = rss[0] * (1.0f / B_) - m * m;
        mean_istd[d] = m;
        mean_istd[64 + d] = rsqrtf(fmaxf(var, 0.0f) + 1e-5f);
    }
}

// ---------------------------------------------------------------------------
// h1 = selu( bn(att) @ inproj_w + inproj_b ). One row per wave.
// ---------------------------------------------------------------------------
__global__ __launch_bounds__(256) void k_inproj(
    const float* __restrict__ att, const float* __restrict__ st,
    const float* __restrict__ bn_g, const float* __restrict__ bn_b,
    const float* __restrict__ W, const float* __restrict__ bias,
    float* __restrict__ h1)
{
    __shared__ float sW[64 * 64];
    __shared__ float sx[4][64];
    const int tid = threadIdx.x, wv = tid >> 6, ln = tid & 63;
    #pragma unroll
    for (int i = 0; i < 16; ++i) sW[tid + 256 * i] = W[tid + 256 * i];
    __syncthreads();

    const int b = blockIdx.x * 4 + wv;
    const float xn = (att[(size_t)b * D_ + ln] - st[ln]) * st[64 + ln] * bn_g[ln] + bn_b[ln];
    sx[wv][ln] = xn;
    __builtin_amdgcn_wave_barrier();
    float acc = bias[ln];
    #pragma unroll 8
    for (int k = 0; k < 64; ++k) acc = fmaf(sx[wv][k], sW[k * 64 + ln], acc);
    h1[(size_t)b * D_ + ln] = seluf_(acc);
}

// ---------------------------------------------------------------------------
// n = bn1(h1) @ outproj + b; self = u2e[nodes]; beta = sigmoid([self|n|self*n]@gate1);
// out = beta*self + (1-beta)*n. One row per wave.
// ---------------------------------------------------------------------------
__global__ __launch_bounds__(256) void k_final(
    const float* __restrict__ h1, const float* __restrict__ st,
    const float* __restrict__ bn1_g, const float* __restrict__ bn1_b,
    const float* __restrict__ Wout, const float* __restrict__ bout,
    const int* __restrict__ nodes, const float* __restrict__ u2e,
    const float* __restrict__ g1w, const float* __restrict__ g1b,
    float* __restrict__ out)
{
    __shared__ float sWo[64 * 64];
    __shared__ float sG[192 * 64];
    __shared__ float sx[4][64];
    __shared__ float sc[4][192];
    const int tid = threadIdx.x, wv = tid >> 6, ln = tid & 63;
    #pragma unroll
    for (int i = 0; i < 16; ++i) sWo[tid + 256 * i] = Wout[tid + 256 * i];
    #pragma unroll
    for (int i = 0; i < 48; ++i) sG[tid + 256 * i] = g1w[tid + 256 * i];
    __syncthreads();

    const int b = blockIdx.x * 4 + wv;
    const float xn = (h1[(size_t)b * D_ + ln] - st[ln]) * st[64 + ln] * bn1_g[ln] + bn1_b[ln];
    sx[wv][ln] = xn;
    __builtin_amdgcn_wave_barrier();
    float acc = bout[ln];
    #pragma unroll 8
    for (int k = 0; k < 64; ++k) acc = fmaf(sx[wv][k], sWo[k * 64 + ln], acc);
    const float nn = acc;
    const float self = u2e[(size_t)nodes[b] * D_ + ln];

    sc[wv][ln] = self;
    sc[wv][64 + ln] = nn;
    sc[wv][128 + ln] = self * nn;
    __builtin_amdgcn_wave_barrier();
    float bacc = g1b[ln];
    #pragma unroll 8
    for (int k = 0; k < 192; ++k) bacc = fmaf(sc[wv][k], sG[k * 64 + ln], bacc);
    const float beta = sigmoidf_(bacc);
    out[(size_t)b * D_ + ln] = beta * self + (1.0f - beta) * nn;
}

extern "C" void kernel_launch(void* const* d_in, const int* in_sizes, int n_in,
                              void* d_out, int out_size, void* d_ws, size_t ws_size,
                              hipStream_t stream) {
    (void)in_sizes; (void)n_in; (void)out_size; (void)ws_size;
    const int*   nodes     = (const int*)d_in[0];
    const int*   hist_ui   = (const int*)d_in[1];
    const int*   hist_r    = (const int*)d_in[2];
    const float* i2e_w     = (const float*)d_in[3];
    const float* u2e_w     = (const float*)d_in[4];
    const float* r2e_w     = (const float*)d_in[5];
    // d_in[6..13]: attention-score MLP params -- dead code (entmax over a
    // size-1 axis == 1.0 identically). Head-1 renorm of unit rows is identity,
    // so att_history = sum_l l2norm(gated fusion).
    const float* gate_w    = (const float*)d_in[14];
    const float* gate_b    = (const float*)d_in[15];
    const float* gate1_w   = (const float*)d_in[16];
    const float* gate1_b   = (const float*)d_in[17];
    const float* bn_g      = (const float*)d_in[18];
    const float* bn_b      = (const float*)d_in[19];
    const float* inproj_w  = (const float*)d_in[20];
    const float* inproj_b  = (const float*)d_in[21];
    const float* bn1_g     = (const float*)d_in[22];
    const float* bn1_b     = (const float*)d_in[23];
    const float* outproj_w = (const float*)d_in[24];
    const float* outproj_b = (const float*)d_in[25];

    float* out    = (float*)d_out;
    float* ws     = (float*)d_ws;
    float* ws_att = ws;                         // B*D floats
    float* ws_h1  = ws + (size_t)B_ * D_;       // B*D floats
    float* st0    = ws + (size_t)2 * B_ * D_;   // 128 floats
    float* st1    = st0 + 128;                  // 128 floats
    float* cbuf   = st1 + 128;                  // 384 floats (16B-aligned)
    unsigned short* wfrag = (unsigned short*)(cbuf + 384);  // 16*64*8 bf16 = 16 KB

    pk_w<<<4, 256, 0, stream>>>(gate_w, wfrag);
    pk_c<<<1, 384, 0, stream>>>(r2e_w, gate_w, gate_b, cbuf);
    k1_fuse<<<B_, 256, 0, stream>>>(hist_ui, hist_r, i2e_w, wfrag, cbuf, r2e_w, ws_att);
    k_stats<<<64, 256, 0, stream>>>(ws_att, st0);
    k_inproj<<<B_ / 4, 256, 0, stream>>>(ws_att, st0, bn_g, bn_b, inproj_w, inproj_b, ws_h1);
    k_stats<<<64, 256, 0, stream>>>(ws_h1, st1);
    k_final<<<B_ / 4, 256, 0, stream>>>(ws_h1, st1, bn1_g, bn1_b, outproj_w, outproj_b,
                                        nodes, u2e_w, gate1_w, gate1_b, out);
}

// Round 3
// 62.128 us; speedup vs baseline: 3.2444x; 1.3340x over previous
//
#include <hip/hip_runtime.h>
#include <hip/hip_bf16.h>

#define B_ 4096
#define L_ 50
#define D_ 64

typedef __attribute__((ext_vector_type(8))) short short8;
typedef __attribute__((ext_vector_type(4))) float f32x4;

__device__ __forceinline__ float sigfast_(float x) {
    return __builtin_amdgcn_rcpf(1.0f + __expf(-x));
}
__device__ __forceinline__ float seluf_(float x) {
    const float sc = 1.0507009873554805f, al = 1.6732632423543772f;
    return x > 0.0f ? sc * x : sc * al * expm1f(x);
}
__device__ __forceinline__ unsigned short bf16_(float f) {
    union { float f; unsigned u; } c; c.f = f;
    unsigned u = c.u + 0x7fff + ((c.u >> 16) & 1);   // RNE
    return (unsigned short)(u >> 16);
}
__device__ __forceinline__ float f32_(unsigned short h) {
    union { unsigned u; float f; } c; c.u = ((unsigned)h) << 16;
    return c.f;
}
__device__ __forceinline__ void split_(float x, unsigned short& hi, unsigned short& lo) {
    hi = bf16_(x);
    lo = bf16_(x - f32_(hi));
}

// ---------------------------------------------------------------------------
// pk_all: one prep kernel, 8 blocks.
//  blk 0-3: gate MFMA A-frags (W'' = [W1; W3], K=128), bf16
//  blk 4  : cbuf[r][d] = gate_b[d] + e_r[r] @ W2   (r<5; slot 5 zero)
//  blk 5/6: inproj / outproj B-frags, bf16 hi+lo split (K=64)
//  blk 7  : gate1 B-frags, bf16 (K=192)
// Frag convention everywhere: 16-index = l&15, k = 32s + 8*(l>>4) + j.
// ---------------------------------------------------------------------------
__global__ __launch_bounds__(256) void pk_all(
    const float* __restrict__ gate_w, const float* __restrict__ gate_b,
    const float* __restrict__ r2e,
    const float* __restrict__ ip_w, const float* __restrict__ op_w,
    const float* __restrict__ g1_w,
    unsigned short* __restrict__ wfrag, float* __restrict__ cbuf,
    unsigned short* __restrict__ ipf_hi, unsigned short* __restrict__ ipf_lo,
    unsigned short* __restrict__ opf_hi, unsigned short* __restrict__ opf_lo,
    unsigned short* __restrict__ g1f)
{
    const int blk = blockIdx.x, tid = threadIdx.x;
    if (blk < 4) {
        const int t = blk * 256 + tid;
        const int rb = t >> 8, s = (t >> 6) & 3, l = t & 63;
        const int dim = 16 * rb + (l & 15);
        short8 o;
        #pragma unroll
        for (int j = 0; j < 8; ++j) {
            int k = 32 * s + 8 * (l >> 4) + j;      // 0..127
            int row = k + (k >= 64 ? 64 : 0);       // W1 rows 0..63, W3 rows 128..191
            o[j] = (short)bf16_(gate_w[row * 64 + dim]);
        }
        reinterpret_cast<short8*>(wfrag)[t] = o;
    } else if (blk == 4) {
        for (int i = tid; i < 384; i += 256) {
            int r = i >> 6, dim = i & 63;
            float acc = 0.0f;
            if (r < 5) {
                acc = gate_b[dim];
                for (int k = 0; k < 64; ++k)
                    acc = fmaf(r2e[r * 64 + k], gate_w[(64 + k) * 64 + dim], acc);
            }
            cbuf[i] = acc;
        }
    } else if (blk == 5 || blk == 6) {
        const float* W = (blk == 5) ? ip_w : op_w;
        unsigned short* H = (blk == 5) ? ipf_hi : opf_hi;
        unsigned short* Lo = (blk == 5) ? ipf_lo : opf_lo;
        for (int e = tid; e < 512; e += 256) {
            int f = e >> 6, l = e & 63, s = f >> 2, nb = f & 3;
            short8 oh, ol;
            #pragma unroll
            for (int j = 0; j < 8; ++j) {
                float w = W[(32 * s + 8 * (l >> 4) + j) * 64 + 16 * nb + (l & 15)];
                unsigned short hi, lo; split_(w, hi, lo);
                oh[j] = (short)hi; ol[j] = (short)lo;
            }
            reinterpret_cast<short8*>(H)[e] = oh;
            reinterpret_cast<short8*>(Lo)[e] = ol;
        }
    } else {
        for (int e = tid; e < 1536; e += 256) {
            int f = e >> 6, l = e & 63, s = f >> 2, nb = f & 3;
            short8 o;
            #pragma unroll
            for (int j = 0; j < 8; ++j)
                o[j] = (short)bf16_(g1_w[(32 * s + 8 * (l >> 4) + j) * 64 + 16 * nb + (l & 15)]);
            reinterpret_cast<short8*>(g1f)[e] = o;
        }
    }
}

// ---------------------------------------------------------------------------
// k1: fused gather + bf16-MFMA gate + fusion + l2norm + sum over L.
// LDS = exactly 32 KiB: sWA[16KB] | sXB[16KB], aliased after MFMA by
// sO (64x68 f32 transpose buffer, stride 68 = conflict-free) + sPart.
// ---------------------------------------------------------------------------
__global__ __launch_bounds__(256) void k1_fuse(
    const int* __restrict__ hist_ui, const int* __restrict__ hist_r,
    const float* __restrict__ i2e,
    const unsigned short* __restrict__ wfrag, const float* __restrict__ cbuf,
    const float* __restrict__ r2e,
    float* __restrict__ ws_att)
{
    __shared__ __align__(16) char smem[32768];
    short8* sWA = reinterpret_cast<short8*>(smem);            // [16*64]
    short8* sXB = reinterpret_cast<short8*>(smem + 16384);    // [16*64]
    float*  sO  = reinterpret_cast<float*>(smem);             // alias: [64][68]
    float*  sPart = reinterpret_cast<float*>(smem + 17408);   // alias: [4][64]

    const int b   = blockIdx.x;
    const int tid = threadIdx.x;
    const int wv  = tid >> 6;
    const int l   = tid & 63;
    const int h   = l >> 4;
    const int c16 = l & 15;

    #pragma unroll
    for (int i = 0; i < 4; ++i)
        sWA[tid + 256 * i] = reinterpret_cast<const short8*>(wfrag)[tid + 256 * i];

    // ---- gather + pack B fragments (wave packs its own 16 rows) ----
    #pragma unroll
    for (int it = 0; it < 4; ++it) {
        const int r15 = it * 4 + h;
        const int br  = wv * 16 + r15;
        const bool valid = br < L_;
        const int iu = valid ? hist_ui[b * L_ + br] : 0;
        const int rr = valid ? hist_r[b * L_ + br] : 0;
        float4 eui = make_float4(0.f, 0.f, 0.f, 0.f);
        if (valid)
            eui = reinterpret_cast<const float4*>(i2e + (size_t)iu * D_)[c16];
        const float4 er = reinterpret_cast<const float4*>(r2e)[rr * 16 + c16];
        const float4 pr = make_float4(eui.x * er.x, eui.y * er.y,
                                      eui.z * er.z, eui.w * er.w);
        const ushort4 be = make_ushort4(bf16_(eui.x), bf16_(eui.y), bf16_(eui.z), bf16_(eui.w));
        const ushort4 bp = make_ushort4(bf16_(pr.x),  bf16_(pr.y),  bf16_(pr.z),  bf16_(pr.w));
        const int o0 = c16 >> 1;
        const int o1 = 8 + (c16 >> 1);
        const int slot0 = (o0 >> 2) * 64 + r15 + 16 * (o0 & 3);
        const int slot1 = (o1 >> 2) * 64 + r15 + 16 * (o1 & 3);
        char* base = smem + 16384 + wv * 4096;
        *reinterpret_cast<ushort4*>(base + slot0 * 16 + (c16 & 1) * 8) = be;
        *reinterpret_cast<ushort4*>(base + slot1 * 16 + (c16 & 1) * 8) = bp;
    }
    __syncthreads();

    // ---- 16 MFMAs ----
    f32x4 acc[4];
    #pragma unroll
    for (int rb = 0; rb < 4; ++rb) acc[rb] = (f32x4){0.f, 0.f, 0.f, 0.f};
    #pragma unroll
    for (int s = 0; s < 4; ++s) {
        const short8 bfrag = sXB[wv * 256 + s * 64 + l];
        #pragma unroll
        for (int rb = 0; rb < 4; ++rb)
            acc[rb] = __builtin_amdgcn_mfma_f32_16x16x32_bf16(
                sWA[(rb * 4 + s) * 64 + l], bfrag, acc[rb], 0, 0, 0);
    }

    // ---- epilogue: sigmoid -> fuse -> l2norm (e_ui re-read as bf16 from sXB) ----
    const int br2 = wv * 16 + c16;
    const float vm = (br2 < L_) ? 1.0f : 0.0f;
    const int rr2 = (br2 < L_) ? hist_r[b * L_ + br2] : 0;
    float o[4][4];
    float ssq = 0.0f;
    #pragma unroll
    for (int rb = 0; rb < 4; ++rb) {
        const int slot = (rb >> 1) * 64 + c16 + 16 * ((2 * rb + (h >> 1)) & 3);
        const ushort4 bu = *reinterpret_cast<const ushort4*>(
            smem + 16384 + wv * 4096 + slot * 16 + (h & 1) * 8);
        const float4 cc  = reinterpret_cast<const float4*>(cbuf)[rr2 * 16 + 4 * rb + h];
        const float4 er4 = reinterpret_cast<const float4*>(r2e)[rr2 * 16 + 4 * rb + h];
        const float eu[4] = { f32_(bu.x), f32_(bu.y), f32_(bu.z), f32_(bu.w) };
        #pragma unroll
        for (int q = 0; q < 4; ++q) {
            const float a  = sigfast_(acc[rb][q] + (&cc.x)[q]);
            const float ov = (a * eu[q] + (1.0f - a) * (&er4.x)[q]) * vm;
            o[rb][q] = ov;
            ssq = fmaf(ov, ov, ssq);
        }
    }
    ssq += __shfl_xor(ssq, 16);
    ssq += __shfl_xor(ssq, 32);
    const float inv = __builtin_amdgcn_rsqf(fmaxf(ssq, 1e-24f));

    __syncthreads();                    // all sWA/sXB reads done -> safe to alias
    const int R = wv * 16 + c16;
    #pragma unroll
    for (int rb = 0; rb < 4; ++rb)
        *reinterpret_cast<float4*>(&sO[R * 68 + 16 * rb + 4 * h]) =
            make_float4(o[rb][0] * inv, o[rb][1] * inv, o[rb][2] * inv, o[rb][3] * inv);
    __builtin_amdgcn_wave_barrier();    // wave reads only its own 16 rows
    float t = 0.0f;
    #pragma unroll
    for (int i = 0; i < 16; ++i) t += sO[(wv * 16 + i) * 68 + l];
    sPart[wv * 64 + l] = t;
    __syncthreads();
    if (tid < 64)
        ws_att[(size_t)b * D_ + tid] =
            sPart[tid] + sPart[64 + tid] + sPart[128 + tid] + sPart[192 + tid];
}

// ---------------------------------------------------------------------------
// k_statsP: coalesced partial sums/sumsq per dim.  32 blocks x 256.
// Thread's float4 always covers dims 4*(tid&15)..+3.
// ---------------------------------------------------------------------------
__global__ __launch_bounds__(256) void k_statsP(const float* __restrict__ x,
                                                float* __restrict__ part)
{
    __shared__ float sA[4][16][8];
    const int tid = threadIdx.x, wv = tid >> 6, l = tid & 63;
    float4 s4 = make_float4(0, 0, 0, 0), q4 = make_float4(0, 0, 0, 0);
    const float4* xv = reinterpret_cast<const float4*>(x);
    const int base = blockIdx.x * 2048 + tid;
    #pragma unroll
    for (int k = 0; k < 8; ++k) {
        float4 v = xv[base + 256 * k];
        s4.x += v.x; s4.y += v.y; s4.z += v.z; s4.w += v.w;
        q4.x = fmaf(v.x, v.x, q4.x); q4.y = fmaf(v.y, v.y, q4.y);
        q4.z = fmaf(v.z, v.z, q4.z); q4.w = fmaf(v.w, v.w, q4.w);
    }
    #define RED_(f) f += __shfl_xor(f, 16); f += __shfl_xor(f, 32);
    RED_(s4.x) RED_(s4.y) RED_(s4.z) RED_(s4.w)
    RED_(q4.x) RED_(q4.y) RED_(q4.z) RED_(q4.w)
    #undef RED_
    if (l < 16) {
        sA[wv][l][0] = s4.x; sA[wv][l][1] = s4.y; sA[wv][l][2] = s4.z; sA[wv][l][3] = s4.w;
        sA[wv][l][4] = q4.x; sA[wv][l][5] = q4.y; sA[wv][l][6] = q4.z; sA[wv][l][7] = q4.w;
    }
    __syncthreads();
    if (tid < 128) {
        const int which = tid >> 6, d = tid & 63;
        float v = 0.f;
        #pragma unroll
        for (int w = 0; w < 4; ++w) v += sA[w][d >> 2][which * 4 + (d & 3)];
        part[blockIdx.x * 128 + tid] = v;
    }
}

// ---------------------------------------------------------------------------
// k_inproj: h1 = selu(bn(att) @ inproj + b) via split-bf16 MFMA (fp32-accurate).
// 64 blocks x 256 (4 waves x 16 rows). Also emits h1 stats partials.
// ---------------------------------------------------------------------------
__global__ __launch_bounds__(256) void k_inproj(
    const float* __restrict__ att, const float* __restrict__ partials1,
    const float* __restrict__ bn_g, const float* __restrict__ bn_b,
    const unsigned short* __restrict__ ipf_hi, const unsigned short* __restrict__ ipf_lo,
    const float* __restrict__ ip_b,
    float* __restrict__ h1, float* __restrict__ partials2)
{
    __shared__ float sSt[128], sTmp[128], sP[4][128];
    const int tid = threadIdx.x, wv = tid >> 6, l = tid & 63;
    const int h = l >> 4, c16 = l & 15;

    if (tid < 128) {
        float s = 0.f;
        for (int k = 0; k < 32; ++k) s += partials1[k * 128 + tid];
        sTmp[tid] = s;
    }
    __syncthreads();
    if (tid < 64) {
        const float m = sTmp[tid] * (1.0f / B_);
        const float var = fmaxf(sTmp[64 + tid] * (1.0f / B_) - m * m, 0.0f);
        const float istd = rsqrtf(var + 1e-5f);
        const float sc = istd * bn_g[tid];
        sSt[tid] = sc; sSt[64 + tid] = bn_b[tid] - m * sc;
    }
    __syncthreads();

    const int r0 = blockIdx.x * 64 + wv * 16;
    const int row = r0 + c16;
    const float4* xr = reinterpret_cast<const float4*>(att + (size_t)row * 64);
    const float4 x0 = xr[2 * h], x1 = xr[2 * h + 1], x2 = xr[8 + 2 * h], x3v = xr[9 + 2 * h];
    const float4* st4 = reinterpret_cast<const float4*>(sSt);
    const float4 sc0 = st4[2 * h], sc1 = st4[2 * h + 1], sh0 = st4[16 + 2 * h], sh1 = st4[17 + 2 * h];
    const float4 sc2 = st4[8 + 2 * h], sc3 = st4[9 + 2 * h], sh2 = st4[24 + 2 * h], sh3 = st4[25 + 2 * h];

    float xn0[8], xn1[8];
    #pragma unroll
    for (int q = 0; q < 4; ++q) {
        xn0[q]     = fmaf((&x0.x)[q], (&sc0.x)[q], (&sh0.x)[q]);
        xn0[4 + q] = fmaf((&x1.x)[q], (&sc1.x)[q], (&sh1.x)[q]);
        xn1[q]     = fmaf((&x2.x)[q], (&sc2.x)[q], (&sh2.x)[q]);
        xn1[4 + q] = fmaf((&x3v.x)[q], (&sc3.x)[q], (&sh3.x)[q]);
    }
    short8 ah0, al0, ah1, al1;
    #pragma unroll
    for (int j = 0; j < 8; ++j) {
        unsigned short hi, lo;
        split_(xn0[j], hi, lo); ah0[j] = (short)hi; al0[j] = (short)lo;
        split_(xn1[j], hi, lo); ah1[j] = (short)hi; al1[j] = (short)lo;
    }

    f32x4 acc[4];
    #pragma unroll
    for (int nb = 0; nb < 4; ++nb) acc[nb] = (f32x4){0.f, 0.f, 0.f, 0.f};
    #pragma unroll
    for (int s = 0; s < 2; ++s) {
        const short8 aH = s ? ah1 : ah0;
        const short8 aL = s ? al1 : al0;
        #pragma unroll
        for (int nb = 0; nb < 4; ++nb) {
            const short8 bh = reinterpret_cast<const short8*>(ipf_hi)[(s * 4 + nb) * 64 + l];
            const short8 bl = reinterpret_cast<const short8*>(ipf_lo)[(s * 4 + nb) * 64 + l];
            acc[nb] = __builtin_amdgcn_mfma_f32_16x16x32_bf16(aH, bh, acc[nb], 0, 0, 0);
            acc[nb] = __builtin_amdgcn_mfma_f32_16x16x32_bf16(aL, bh, acc[nb], 0, 0, 0);
            acc[nb] = __builtin_amdgcn_mfma_f32_16x16x32_bf16(aH, bl, acc[nb], 0, 0, 0);
        }
    }

    #pragma unroll
    for (int nb = 0; nb < 4; ++nb) {
        const int dim = 16 * nb + c16;
        const float bias = ip_b[dim];
        float sl = 0.f, sq = 0.f;
        #pragma unroll
        for (int r = 0; r < 4; ++r) {
            const float v = seluf_(acc[nb][r] + bias);
            h1[(size_t)(r0 + 4 * h + r) * 64 + dim] = v;
            sl += v; sq = fmaf(v, v, sq);
        }
        sl += __shfl_xor(sl, 16); sl += __shfl_xor(sl, 32);
        sq += __shfl_xor(sq, 16); sq += __shfl_xor(sq, 32);
        if (l < 16) { sP[wv][16 * nb + l] = sl; sP[wv][64 + 16 * nb + l] = sq; }
    }
    __syncthreads();
    if (tid < 128)
        partials2[blockIdx.x * 128 + tid] =
            sP[0][tid] + sP[1][tid] + sP[2][tid] + sP[3][tid];
}

// ---------------------------------------------------------------------------
// k_final: n = bn1(h1)@outproj+b (split-bf16); self=u2e[nodes];
// beta = sigmoid([self|n|self*n]@gate1+b) (bf16); out = beta*self+(1-beta)*n.
// 64 blocks x 256 (4 waves x 16 rows). X3 concat staged bf16 in per-wave LDS.
// ---------------------------------------------------------------------------
__global__ __launch_bounds__(256) void k_final(
    const float* __restrict__ h1, const float* __restrict__ partials2,
    const float* __restrict__ bn1_g, const float* __restrict__ bn1_b,
    const unsigned short* __restrict__ opf_hi, const unsigned short* __restrict__ opf_lo,
    const float* __restrict__ op_b,
    const int* __restrict__ nodes, const float* __restrict__ u2e,
    const unsigned short* __restrict__ g1f, const float* __restrict__ g1_b,
    float* __restrict__ out)
{
    __shared__ float sSt[128], sTmp[128];
    __shared__ __align__(16) unsigned short sX3[4][16 * 200];
    const int tid = threadIdx.x, wv = tid >> 6, l = tid & 63;
    const int h = l >> 4, c16 = l & 15;

    if (tid < 128) {
        float s = 0.f;
        for (int k = 0; k < 64; ++k) s += partials2[k * 128 + tid];
        sTmp[tid] = s;
    }
    __syncthreads();
    if (tid < 64) {
        const float m = sTmp[tid] * (1.0f / B_);
        const float var = fmaxf(sTmp[64 + tid] * (1.0f / B_) - m * m, 0.0f);
        const float istd = rsqrtf(var + 1e-5f);
        const float sc = istd * bn1_g[tid];
        sSt[tid] = sc; sSt[64 + tid] = bn1_b[tid] - m * sc;
    }
    __syncthreads();

    const int r0 = blockIdx.x * 64 + wv * 16;
    const int row = r0 + c16;
    const float4* xr = reinterpret_cast<const float4*>(h1 + (size_t)row * 64);
    const float4 x0 = xr[2 * h], x1 = xr[2 * h + 1], x2 = xr[8 + 2 * h], x3v = xr[9 + 2 * h];
    const float4* st4 = reinterpret_cast<const float4*>(sSt);
    const float4 sc0 = st4[2 * h], sc1 = st4[2 * h + 1], sh0 = st4[16 + 2 * h], sh1 = st4[17 + 2 * h];
    const float4 sc2 = st4[8 + 2 * h], sc3 = st4[9 + 2 * h], sh2 = st4[24 + 2 * h], sh3 = st4[25 + 2 * h];

    float xn0[8], xn1[8];
    #pragma unroll
    for (int q = 0; q < 4; ++q) {
        xn0[q]     = fmaf((&x0.x)[q], (&sc0.x)[q], (&sh0.x)[q]);
        xn0[4 + q] = fmaf((&x1.x)[q], (&sc1.x)[q], (&sh1.x)[q]);
        xn1[q]     = fmaf((&x2.x)[q], (&sc2.x)[q], (&sh2.x)[q]);
        xn1[4 + q] = fmaf((&x3v.x)[q], (&sc3.x)[q], (&sh3.x)[q]);
    }
    short8 ah0, al0, ah1, al1;
    #pragma unroll
    for (int j = 0; j < 8; ++j) {
        unsigned short hi, lo;
        split_(xn0[j], hi, lo); ah0[j] = (short)hi; al0[j] = (short)lo;
        split_(xn1[j], hi, lo); ah1[j] = (short)hi; al1[j] = (short)lo;
    }

    f32x4 acc[4];
    #pragma unroll
    for (int nb = 0; nb < 4; ++nb) acc[nb] = (f32x4){0.f, 0.f, 0.f, 0.f};
    #pragma unroll
    for (int s = 0; s < 2; ++s) {
        const short8 aH = s ? ah1 : ah0;
        const short8 aL = s ? al1 : al0;
        #pragma unroll
        for (int nb = 0; nb < 4; ++nb) {
            const short8 bh = reinterpret_cast<const short8*>(opf_hi)[(s * 4 + nb) * 64 + l];
            const short8 bl = reinterpret_cast<const short8*>(opf_lo)[(s * 4 + nb) * 64 + l];
            acc[nb] = __builtin_amdgcn_mfma_f32_16x16x32_bf16(aH, bh, acc[nb], 0, 0, 0);
            acc[nb] = __builtin_amdgcn_mfma_f32_16x16x32_bf16(aL, bh, acc[nb], 0, 0, 0);
            acc[nb] = __builtin_amdgcn_mfma_f32_16x16x32_bf16(aH, bl, acc[nb], 0, 0, 0);
        }
    }

    int nd[4];
    #pragma unroll
    for (int r = 0; r < 4; ++r) nd[r] = nodes[r0 + 4 * h + r];

    float nn[4][4], sf[4][4];
    unsigned short* X = sX3[wv];
    #pragma unroll
    for (int nb = 0; nb < 4; ++nb) {
        const int dim = 16 * nb + c16;
        const float bias = op_b[dim];
        #pragma unroll
        for (int r = 0; r < 4; ++r) {
            const float v = acc[nb][r] + bias;
            const float s = u2e[(size_t)nd[r] * 64 + dim];
            nn[nb][r] = v; sf[nb][r] = s;
            const int rI = 4 * h + r;
            X[rI * 200 + dim]       = bf16_(s);
            X[rI * 200 + 64 + dim]  = bf16_(v);
            X[rI * 200 + 128 + dim] = bf16_(s * v);
        }
    }
    __builtin_amdgcn_wave_barrier();
    __syncthreads();   // conservative: ensure LDS writes visible before frag reads

    f32x4 acc3[4];
    #pragma unroll
    for (int nb = 0; nb < 4; ++nb) acc3[nb] = (f32x4){0.f, 0.f, 0.f, 0.f};
    #pragma unroll
    for (int s = 0; s < 6; ++s) {
        const short8 a3 = *reinterpret_cast<const short8*>(&sX3[wv][c16 * 200 + 32 * s + 8 * h]);
        #pragma unroll
        for (int nb = 0; nb < 4; ++nb)
            acc3[nb] = __builtin_amdgcn_mfma_f32_16x16x32_bf16(
                a3, reinterpret_cast<const short8*>(g1f)[(s * 4 + nb) * 64 + l], acc3[nb], 0, 0, 0);
    }

    #pragma unroll
    for (int nb = 0; nb < 4; ++nb) {
        const int dim = 16 * nb + c16;
        const float gb = g1_b[dim];
        #pragma unroll
        for (int r = 0; r < 4; ++r) {
            const float beta = sigfast_(acc3[nb][r] + gb);
            out[(size_t)(r0 + 4 * h + r) * 64 + dim] =
                beta * sf[nb][r] + (1.0f - beta) * nn[nb][r];
        }
    }
}

extern "C" void kernel_launch(void* const* d_in, const int* in_sizes, int n_in,
                              void* d_out, int out_size, void* d_ws, size_t ws_size,
                              hipStream_t stream) {
    (void)in_sizes; (void)n_in; (void)out_size; (void)ws_size;
    const int*   nodes     = (const int*)d_in[0];
    const int*   hist_ui   = (const int*)d_in[1];
    const int*   hist_r    = (const int*)d_in[2];
    const float* i2e_w     = (const float*)d_in[3];
    const float* u2e_w     = (const float*)d_in[4];
    const float* r2e_w     = (const float*)d_in[5];
    // d_in[6..13]: attention-score MLP params -- dead code (entmax over a
    // size-1 axis == 1.0 identically; head-1 renorm of unit vectors is identity).
    const float* gate_w    = (const float*)d_in[14];
    const float* gate_b    = (const float*)d_in[15];
    const float* gate1_w   = (const float*)d_in[16];
    const float* gate1_b   = (const float*)d_in[17];
    const float* bn_g      = (const float*)d_in[18];
    const float* bn_b      = (const float*)d_in[19];
    const float* inproj_w  = (const float*)d_in[20];
    const float* inproj_b  = (const float*)d_in[21];
    const float* bn1_g     = (const float*)d_in[22];
    const float* bn1_b     = (const float*)d_in[23];
    const float* outproj_w = (const float*)d_in[24];
    const float* outproj_b = (const float*)d_in[25];

    float* out = (float*)d_out;
    float* ws  = (float*)d_ws;
    float* ws_att = ws;                              // 262144
    float* ws_h1  = ws + 262144;                     // 262144
    float* cbuf   = ws + 524288;                     // 384
    unsigned short* wfrag  = (unsigned short*)(ws + 524672);  // 16 KB
    unsigned short* ipf_hi = (unsigned short*)(ws + 528768);  // 8 KB
    unsigned short* ipf_lo = (unsigned short*)(ws + 530816);  // 8 KB
    unsigned short* opf_hi = (unsigned short*)(ws + 532864);  // 8 KB
    unsigned short* opf_lo = (unsigned short*)(ws + 534912);  // 8 KB
    unsigned short* g1f    = (unsigned short*)(ws + 536960);  // 24 KB
    float* partials1 = ws + 543104;                  // 32*128
    float* partials2 = ws + 547200;                  // 64*128

    pk_all<<<8, 256, 0, stream>>>(gate_w, gate_b, r2e_w, inproj_w, outproj_w, gate1_w,
                                  wfrag, cbuf, ipf_hi, ipf_lo, opf_hi, opf_lo, g1f);
    k1_fuse<<<B_, 256, 0, stream>>>(hist_ui, hist_r, i2e_w, wfrag, cbuf, r2e_w, ws_att);
    k_statsP<<<32, 256, 0, stream>>>(ws_att, partials1);
    k_inproj<<<64, 256, 0, stream>>>(ws_att, partials1, bn_g, bn_b, ipf_hi, ipf_lo,
                                     inproj_b, ws_h1, partials2);
    k_final<<<64, 256, 0, stream>>>(ws_h1, partials2, bn1_g, bn1_b, opf_hi, opf_lo,
                                    outproj_b, nodes, u2e_w, g1f, gate1_b, out);
}

// Round 4
// 58.529 us; speedup vs baseline: 3.4439x; 1.0615x over previous
//
#include <hip/hip_runtime.h>
#include <hip/hip_bf16.h>

#define B_ 4096
#define L_ 50
#define D_ 64

typedef __attribute__((ext_vector_type(8))) short short8;
typedef __attribute__((ext_vector_type(4))) float f32x4;

__device__ __forceinline__ float sigfast_(float x) {
    return __builtin_amdgcn_rcpf(1.0f + __expf(-x));
}
__device__ __forceinline__ float seluf_(float x) {
    const float sc = 1.0507009873554805f, al = 1.6732632423543772f;
    return x > 0.0f ? sc * x : sc * al * expm1f(x);
}
__device__ __forceinline__ unsigned short bf16_(float f) {
    union { float f; unsigned u; } c; c.f = f;
    unsigned u = c.u + 0x7fff + ((c.u >> 16) & 1);   // RNE
    return (unsigned short)(u >> 16);
}
__device__ __forceinline__ float f32_(unsigned short h) {
    union { unsigned u; float f; } c; c.u = ((unsigned)h) << 16;
    return c.f;
}
__device__ __forceinline__ void split_(float x, unsigned short& hi, unsigned short& lo) {
    hi = bf16_(x);
    lo = bf16_(x - f32_(hi));
}
// packed f32->bf16 convert (RNE), 2 values per instruction
__device__ __forceinline__ unsigned pk2_(float lo, float hi) {
    unsigned r;
    asm("v_cvt_pk_bf16_f32 %0, %1, %2" : "=v"(r) : "v"(lo), "v"(hi));
    return r;
}
__device__ __forceinline__ short8 pk8_(float4 a, float4 b) {
    union { unsigned u[4]; short8 s; } cv;
    cv.u[0] = pk2_(a.x, a.y); cv.u[1] = pk2_(a.z, a.w);
    cv.u[2] = pk2_(b.x, b.y); cv.u[3] = pk2_(b.z, b.w);
    return cv.s;
}

// ---------------------------------------------------------------------------
// pk_all: one prep kernel, 8 blocks (unchanged from R3).
// ---------------------------------------------------------------------------
__global__ __launch_bounds__(256) void pk_all(
    const float* __restrict__ gate_w, const float* __restrict__ gate_b,
    const float* __restrict__ r2e,
    const float* __restrict__ ip_w, const float* __restrict__ op_w,
    const float* __restrict__ g1_w,
    unsigned short* __restrict__ wfrag, float* __restrict__ cbuf,
    unsigned short* __restrict__ ipf_hi, unsigned short* __restrict__ ipf_lo,
    unsigned short* __restrict__ opf_hi, unsigned short* __restrict__ opf_lo,
    unsigned short* __restrict__ g1f)
{
    const int blk = blockIdx.x, tid = threadIdx.x;
    if (blk < 4) {
        const int t = blk * 256 + tid;
        const int rb = t >> 8, s = (t >> 6) & 3, l = t & 63;
        const int dim = 16 * rb + (l & 15);
        short8 o;
        #pragma unroll
        for (int j = 0; j < 8; ++j) {
            int k = 32 * s + 8 * (l >> 4) + j;      // 0..127
            int row = k + (k >= 64 ? 64 : 0);       // W1 rows 0..63, W3 rows 128..191
            o[j] = (short)bf16_(gate_w[row * 64 + dim]);
        }
        reinterpret_cast<short8*>(wfrag)[t] = o;
    } else if (blk == 4) {
        for (int i = tid; i < 384; i += 256) {
            int r = i >> 6, dim = i & 63;
            float acc = 0.0f;
            if (r < 5) {
                acc = gate_b[dim];
                for (int k = 0; k < 64; ++k)
                    acc = fmaf(r2e[r * 64 + k], gate_w[(64 + k) * 64 + dim], acc);
            }
            cbuf[i] = acc;
        }
    } else if (blk == 5 || blk == 6) {
        const float* W = (blk == 5) ? ip_w : op_w;
        unsigned short* H = (blk == 5) ? ipf_hi : opf_hi;
        unsigned short* Lo = (blk == 5) ? ipf_lo : opf_lo;
        for (int e = tid; e < 512; e += 256) {
            int f = e >> 6, l = e & 63, s = f >> 2, nb = f & 3;
            short8 oh, ol;
            #pragma unroll
            for (int j = 0; j < 8; ++j) {
                float w = W[(32 * s + 8 * (l >> 4) + j) * 64 + 16 * nb + (l & 15)];
                unsigned short hi, lo; split_(w, hi, lo);
                oh[j] = (short)hi; ol[j] = (short)lo;
            }
            reinterpret_cast<short8*>(H)[e] = oh;
            reinterpret_cast<short8*>(Lo)[e] = ol;
        }
    } else {
        for (int e = tid; e < 1536; e += 256) {
            int f = e >> 6, l = e & 63, s = f >> 2, nb = f & 3;
            short8 o;
            #pragma unroll
            for (int j = 0; j < 8; ++j)
                o[j] = (short)bf16_(g1_w[(32 * s + 8 * (l >> 4) + j) * 64 + 16 * nb + (l & 15)]);
            reinterpret_cast<short8*>(g1f)[e] = o;
        }
    }
}

// ---------------------------------------------------------------------------
// k1: fused gather + bf16-MFMA gate + fusion + l2norm + sum over L.
// B-fragments built ENTIRELY in registers from the gather (no LDS pack):
// lane (h,c16) of wave wv owns batch-row r = wv*16+c16 and gathers e_ui/e_r
// chunks [8h..8h+7] and [32+8h..+7] -- exactly the k-slices frags s=0..3 need.
// LDS: sWA (W-frags, 16 KB) + sPart (1 KB). 2 barriers total.
// ---------------------------------------------------------------------------
__global__ __launch_bounds__(256) void k1_fuse(
    const int* __restrict__ hist_ui, const int* __restrict__ hist_r,
    const float* __restrict__ i2e,
    const unsigned short* __restrict__ wfrag, const float* __restrict__ cbuf,
    const float* __restrict__ r2e,
    float* __restrict__ ws_att)
{
    __shared__ short8 sWA[16 * 64];                 // 16 KB
    __shared__ __align__(16) float sPart[4][64];    // 1 KB

    const int b   = blockIdx.x;
    const int tid = threadIdx.x;
    const int wv  = tid >> 6;
    const int l   = tid & 63;
    const int h   = l >> 4;
    const int c16 = l & 15;

    const int row = wv * 16 + c16;                  // this lane's batch-row
    const bool valid = row < L_;
    int iu = 0, rr = 0;
    if (valid) {
        iu = hist_ui[b * L_ + row];
        rr = hist_r[b * L_ + row];
    }

    #pragma unroll
    for (int i = 0; i < 4; ++i)
        sWA[tid + 256 * i] = reinterpret_cast<const short8*>(wfrag)[tid + 256 * i];

    // ---- gather directly in fragment layout ----
    float4 f0 = make_float4(0,0,0,0), f1 = f0, f2 = f0, f3 = f0;
    float4 r0 = f0, r1 = f0, r2 = f0, r3 = f0;
    const float4* gp = reinterpret_cast<const float4*>(i2e + (size_t)iu * D_);
    const float4* rp = reinterpret_cast<const float4*>(r2e + rr * D_);
    if (valid) {
        f0 = gp[2 * h];     f1 = gp[2 * h + 1];
        f2 = gp[8 + 2 * h]; f3 = gp[9 + 2 * h];
        r0 = rp[2 * h];     r1 = rp[2 * h + 1];
        r2 = rp[8 + 2 * h]; r3 = rp[9 + 2 * h];
    }
    const float4 p0 = make_float4(f0.x*r0.x, f0.y*r0.y, f0.z*r0.z, f0.w*r0.w);
    const float4 p1 = make_float4(f1.x*r1.x, f1.y*r1.y, f1.z*r1.z, f1.w*r1.w);
    const float4 p2 = make_float4(f2.x*r2.x, f2.y*r2.y, f2.z*r2.z, f2.w*r2.w);
    const float4 p3 = make_float4(f3.x*r3.x, f3.y*r3.y, f3.z*r3.z, f3.w*r3.w);
    const short8 bf[4] = { pk8_(f0, f1), pk8_(f2, f3), pk8_(p0, p1), pk8_(p2, p3) };

    __syncthreads();                                // sWA visible

    // ---- 16 MFMAs, B from registers ----
    f32x4 acc[4];
    #pragma unroll
    for (int rb = 0; rb < 4; ++rb) acc[rb] = (f32x4){0.f, 0.f, 0.f, 0.f};
    #pragma unroll
    for (int s = 0; s < 4; ++s) {
        #pragma unroll
        for (int rb = 0; rb < 4; ++rb)
            acc[rb] = __builtin_amdgcn_mfma_f32_16x16x32_bf16(
                sWA[(rb * 4 + s) * 64 + l], bf[s], acc[rb], 0, 0, 0);
    }

    // ---- epilogue: sigmoid -> fuse (fp32 operands) -> l2norm -> row-sum ----
    float o[4][4];
    float ssq = 0.0f;
    #pragma unroll
    for (int rb = 0; rb < 4; ++rb) {
        float4 eu4 = make_float4(0,0,0,0), er4 = eu4, cc = eu4;
        if (valid) {
            eu4 = gp[4 * rb + h];
            er4 = rp[4 * rb + h];
            cc  = reinterpret_cast<const float4*>(cbuf)[rr * 16 + 4 * rb + h];
        }
        #pragma unroll
        for (int q = 0; q < 4; ++q) {
            const float a  = sigfast_(acc[rb][q] + (&cc.x)[q]);
            const float ov = a * (&eu4.x)[q] + (1.0f - a) * (&er4.x)[q];
            o[rb][q] = ov;
            ssq = fmaf(ov, ov, ssq);
        }
    }
    ssq += __shfl_xor(ssq, 16);                     // sum over h -> per-row ssq
    ssq += __shfl_xor(ssq, 32);
    const float inv = __builtin_amdgcn_rsqf(fmaxf(ssq, 1e-24f));

    #pragma unroll
    for (int rb = 0; rb < 4; ++rb)
        #pragma unroll
        for (int q = 0; q < 4; ++q) {
            float v = o[rb][q] * inv;
            v += __shfl_xor(v, 1); v += __shfl_xor(v, 2);
            v += __shfl_xor(v, 4); v += __shfl_xor(v, 8);   // sum over 16 rows
            o[rb][q] = v;
        }
    if (c16 == 0) {
        #pragma unroll
        for (int rb = 0; rb < 4; ++rb)
            reinterpret_cast<float4*>(sPart[wv])[4 * rb + h] =
                make_float4(o[rb][0], o[rb][1], o[rb][2], o[rb][3]);
    }
    __syncthreads();
    if (tid < 64)
        ws_att[(size_t)b * D_ + tid] =
            sPart[0][tid] + sPart[1][tid] + sPart[2][tid] + sPart[3][tid];
}

// ---------------------------------------------------------------------------
// k_statsP: coalesced partial sums/sumsq per dim.  32 blocks x 256.
// ---------------------------------------------------------------------------
__global__ __launch_bounds__(256) void k_statsP(const float* __restrict__ x,
                                                float* __restrict__ part)
{
    __shared__ float sA[4][16][8];
    const int tid = threadIdx.x, wv = tid >> 6, l = tid & 63;
    float4 s4 = make_float4(0, 0, 0, 0), q4 = make_float4(0, 0, 0, 0);
    const float4* xv = reinterpret_cast<const float4*>(x);
    const int base = blockIdx.x * 2048 + tid;
    #pragma unroll
    for (int k = 0; k < 8; ++k) {
        float4 v = xv[base + 256 * k];
        s4.x += v.x; s4.y += v.y; s4.z += v.z; s4.w += v.w;
        q4.x = fmaf(v.x, v.x, q4.x); q4.y = fmaf(v.y, v.y, q4.y);
        q4.z = fmaf(v.z, v.z, q4.z); q4.w = fmaf(v.w, v.w, q4.w);
    }
    #define RED_(f) f += __shfl_xor(f, 16); f += __shfl_xor(f, 32);
    RED_(s4.x) RED_(s4.y) RED_(s4.z) RED_(s4.w)
    RED_(q4.x) RED_(q4.y) RED_(q4.z) RED_(q4.w)
    #undef RED_
    if (l < 16) {
        sA[wv][l][0] = s4.x; sA[wv][l][1] = s4.y; sA[wv][l][2] = s4.z; sA[wv][l][3] = s4.w;
        sA[wv][l][4] = q4.x; sA[wv][l][5] = q4.y; sA[wv][l][6] = q4.z; sA[wv][l][7] = q4.w;
    }
    __syncthreads();
    if (tid < 128) {
        const int which = tid >> 6, d = tid & 63;
        float v = 0.f;
        #pragma unroll
        for (int w = 0; w < 4; ++w) v += sA[w][d >> 2][which * 4 + (d & 3)];
        part[blockIdx.x * 128 + tid] = v;
    }
}

// ---------------------------------------------------------------------------
// k_inproj: h1 = selu(bn(att) @ inproj + b) via split-bf16 MFMA.
// ---------------------------------------------------------------------------
__global__ __launch_bounds__(256) void k_inproj(
    const float* __restrict__ att, const float* __restrict__ partials1,
    const float* __restrict__ bn_g, const float* __restrict__ bn_b,
    const unsigned short* __restrict__ ipf_hi, const unsigned short* __restrict__ ipf_lo,
    const float* __restrict__ ip_b,
    float* __restrict__ h1, float* __restrict__ partials2)
{
    __shared__ float sSt[128], sTmp[128], sP[4][128];
    const int tid = threadIdx.x, wv = tid >> 6, l = tid & 63;
    const int h = l >> 4, c16 = l & 15;

    if (tid < 128) {
        float s = 0.f;
        for (int k = 0; k < 32; ++k) s += partials1[k * 128 + tid];
        sTmp[tid] = s;
    }
    __syncthreads();
    if (tid < 64) {
        const float m = sTmp[tid] * (1.0f / B_);
        const float var = fmaxf(sTmp[64 + tid] * (1.0f / B_) - m * m, 0.0f);
        const float istd = rsqrtf(var + 1e-5f);
        const float sc = istd * bn_g[tid];
        sSt[tid] = sc; sSt[64 + tid] = bn_b[tid] - m * sc;
    }
    __syncthreads();

    const int r0 = blockIdx.x * 64 + wv * 16;
    const int row = r0 + c16;
    const float4* xr = reinterpret_cast<const float4*>(att + (size_t)row * 64);
    const float4 x0 = xr[2 * h], x1 = xr[2 * h + 1], x2 = xr[8 + 2 * h], x3v = xr[9 + 2 * h];
    const float4* st4 = reinterpret_cast<const float4*>(sSt);
    const float4 sc0 = st4[2 * h], sc1 = st4[2 * h + 1], sh0 = st4[16 + 2 * h], sh1 = st4[17 + 2 * h];
    const float4 sc2 = st4[8 + 2 * h], sc3 = st4[9 + 2 * h], sh2 = st4[24 + 2 * h], sh3 = st4[25 + 2 * h];

    float xn0[8], xn1[8];
    #pragma unroll
    for (int q = 0; q < 4; ++q) {
        xn0[q]     = fmaf((&x0.x)[q], (&sc0.x)[q], (&sh0.x)[q]);
        xn0[4 + q] = fmaf((&x1.x)[q], (&sc1.x)[q], (&sh1.x)[q]);
        xn1[q]     = fmaf((&x2.x)[q], (&sc2.x)[q], (&sh2.x)[q]);
        xn1[4 + q] = fmaf((&x3v.x)[q], (&sc3.x)[q], (&sh3.x)[q]);
    }
    short8 ah0, al0, ah1, al1;
    #pragma unroll
    for (int j = 0; j < 8; ++j) {
        unsigned short hi, lo;
        split_(xn0[j], hi, lo); ah0[j] = (short)hi; al0[j] = (short)lo;
        split_(xn1[j], hi, lo); ah1[j] = (short)hi; al1[j] = (short)lo;
    }

    f32x4 acc[4];
    #pragma unroll
    for (int nb = 0; nb < 4; ++nb) acc[nb] = (f32x4){0.f, 0.f, 0.f, 0.f};
    #pragma unroll
    for (int s = 0; s < 2; ++s) {
        const short8 aH = s ? ah1 : ah0;
        const short8 aL = s ? al1 : al0;
        #pragma unroll
        for (int nb = 0; nb < 4; ++nb) {
            const short8 bh = reinterpret_cast<const short8*>(ipf_hi)[(s * 4 + nb) * 64 + l];
            const short8 bl = reinterpret_cast<const short8*>(ipf_lo)[(s * 4 + nb) * 64 + l];
            acc[nb] = __builtin_amdgcn_mfma_f32_16x16x32_bf16(aH, bh, acc[nb], 0, 0, 0);
            acc[nb] = __builtin_amdgcn_mfma_f32_16x16x32_bf16(aL, bh, acc[nb], 0, 0, 0);
            acc[nb] = __builtin_amdgcn_mfma_f32_16x16x32_bf16(aH, bl, acc[nb], 0, 0, 0);
        }
    }

    #pragma unroll
    for (int nb = 0; nb < 4; ++nb) {
        const int dim = 16 * nb + c16;
        const float bias = ip_b[dim];
        float sl = 0.f, sq = 0.f;
        #pragma unroll
        for (int r = 0; r < 4; ++r) {
            const float v = seluf_(acc[nb][r] + bias);
            h1[(size_t)(r0 + 4 * h + r) * 64 + dim] = v;
            sl += v; sq = fmaf(v, v, sq);
        }
        sl += __shfl_xor(sl, 16); sl += __shfl_xor(sl, 32);
        sq += __shfl_xor(sq, 16); sq += __shfl_xor(sq, 32);
        if (l < 16) { sP[wv][16 * nb + l] = sl; sP[wv][64 + 16 * nb + l] = sq; }
    }
    __syncthreads();
    if (tid < 128)
        partials2[blockIdx.x * 128 + tid] =
            sP[0][tid] + sP[1][tid] + sP[2][tid] + sP[3][tid];
}

// ---------------------------------------------------------------------------
// k_final: n = bn1(h1)@outproj+b (split-bf16); beta via gate1 (bf16);
// out = beta*self + (1-beta)*n.
// ---------------------------------------------------------------------------
__global__ __launch_bounds__(256) void k_final(
    const float* __restrict__ h1, const float* __restrict__ partials2,
    const float* __restrict__ bn1_g, const float* __restrict__ bn1_b,
    const unsigned short* __restrict__ opf_hi, const unsigned short* __restrict__ opf_lo,
    const float* __restrict__ op_b,
    const int* __restrict__ nodes, const float* __restrict__ u2e,
    const unsigned short* __restrict__ g1f, const float* __restrict__ g1_b,
    float* __restrict__ out)
{
    __shared__ float sSt[128], sTmp[128];
    __shared__ __align__(16) unsigned short sX3[4][16 * 200];
    const int tid = threadIdx.x, wv = tid >> 6, l = tid & 63;
    const int h = l >> 4, c16 = l & 15;

    if (tid < 128) {
        float s = 0.f;
        for (int k = 0; k < 64; ++k) s += partials2[k * 128 + tid];
        sTmp[tid] = s;
    }
    __syncthreads();
    if (tid < 64) {
        const float m = sTmp[tid] * (1.0f / B_);
        const float var = fmaxf(sTmp[64 + tid] * (1.0f / B_) - m * m, 0.0f);
        const float istd = rsqrtf(var + 1e-5f);
        const float sc = istd * bn1_g[tid];
        sSt[tid] = sc; sSt[64 + tid] = bn1_b[tid] - m * sc;
    }
    __syncthreads();

    const int r0 = blockIdx.x * 64 + wv * 16;
    const int row = r0 + c16;
    const float4* xr = reinterpret_cast<const float4*>(h1 + (size_t)row * 64);
    const float4 x0 = xr[2 * h], x1 = xr[2 * h + 1], x2 = xr[8 + 2 * h], x3v = xr[9 + 2 * h];
    const float4* st4 = reinterpret_cast<const float4*>(sSt);
    const float4 sc0 = st4[2 * h], sc1 = st4[2 * h + 1], sh0 = st4[16 + 2 * h], sh1 = st4[17 + 2 * h];
    const float4 sc2 = st4[8 + 2 * h], sc3 = st4[9 + 2 * h], sh2 = st4[24 + 2 * h], sh3 = st4[25 + 2 * h];

    float xn0[8], xn1[8];
    #pragma unroll
    for (int q = 0; q < 4; ++q) {
        xn0[q]     = fmaf((&x0.x)[q], (&sc0.x)[q], (&sh0.x)[q]);
        xn0[4 + q] = fmaf((&x1.x)[q], (&sc1.x)[q], (&sh1.x)[q]);
        xn1[q]     = fmaf((&x2.x)[q], (&sc2.x)[q], (&sh2.x)[q]);
        xn1[4 + q] = fmaf((&x3v.x)[q], (&sc3.x)[q], (&sh3.x)[q]);
    }
    short8 ah0, al0, ah1, al1;
    #pragma unroll
    for (int j = 0; j < 8; ++j) {
        unsigned short hi, lo;
        split_(xn0[j], hi, lo); ah0[j] = (short)hi; al0[j] = (short)lo;
        split_(xn1[j], hi, lo); ah1[j] = (short)hi; al1[j] = (short)lo;
    }

    f32x4 acc[4];
    #pragma unroll
    for (int nb = 0; nb < 4; ++nb) acc[nb] = (f32x4){0.f, 0.f, 0.f, 0.f};
    #pragma unroll
    for (int s = 0; s < 2; ++s) {
        const short8 aH = s ? ah1 : ah0;
        const short8 aL = s ? al1 : al0;
        #pragma unroll
        for (int nb = 0; nb < 4; ++nb) {
            const short8 bh = reinterpret_cast<const short8*>(opf_hi)[(s * 4 + nb) * 64 + l];
            const short8 bl = reinterpret_cast<const short8*>(opf_lo)[(s * 4 + nb) * 64 + l];
            acc[nb] = __builtin_amdgcn_mfma_f32_16x16x32_bf16(aH, bh, acc[nb], 0, 0, 0);
            acc[nb] = __builtin_amdgcn_mfma_f32_16x16x32_bf16(aL, bh, acc[nb], 0, 0, 0);
            acc[nb] = __builtin_amdgcn_mfma_f32_16x16x32_bf16(aH, bl, acc[nb], 0, 0, 0);
        }
    }

    int nd[4];
    #pragma unroll
    for (int r = 0; r < 4; ++r) nd[r] = nodes[r0 + 4 * h + r];

    float nn[4][4], sf[4][4];
    unsigned short* X = sX3[wv];
    #pragma unroll
    for (int nb = 0; nb < 4; ++nb) {
        const int dim = 16 * nb + c16;
        const float bias = op_b[dim];
        #pragma unroll
        for (int r = 0; r < 4; ++r) {
            const float v = acc[nb][r] + bias;
            const float s = u2e[(size_t)nd[r] * 64 + dim];
            nn[nb][r] = v; sf[nb][r] = s;
            const int rI = 4 * h + r;
            X[rI * 200 + dim]       = bf16_(s);
            X[rI * 200 + 64 + dim]  = bf16_(v);
            X[rI * 200 + 128 + dim] = bf16_(s * v);
        }
    }
    __builtin_amdgcn_wave_barrier();
    __syncthreads();

    f32x4 acc3[4];
    #pragma unroll
    for (int nb = 0; nb < 4; ++nb) acc3[nb] = (f32x4){0.f, 0.f, 0.f, 0.f};
    #pragma unroll
    for (int s = 0; s < 6; ++s) {
        const short8 a3 = *reinterpret_cast<const short8*>(&sX3[wv][c16 * 200 + 32 * s + 8 * h]);
        #pragma unroll
        for (int nb = 0; nb < 4; ++nb)
            acc3[nb] = __builtin_amdgcn_mfma_f32_16x16x32_bf16(
                a3, reinterpret_cast<const short8*>(g1f)[(s * 4 + nb) * 64 + l], acc3[nb], 0, 0, 0);
    }

    #pragma unroll
    for (int nb = 0; nb < 4; ++nb) {
        const int dim = 16 * nb + c16;
        const float gb = g1_b[dim];
        #pragma unroll
        for (int r = 0; r < 4; ++r) {
            const float beta = sigfast_(acc3[nb][r] + gb);
            out[(size_t)(r0 + 4 * h + r) * 64 + dim] =
                beta * sf[nb][r] + (1.0f - beta) * nn[nb][r];
        }
    }
}

extern "C" void kernel_launch(void* const* d_in, const int* in_sizes, int n_in,
                              void* d_out, int out_size, void* d_ws, size_t ws_size,
                              hipStream_t stream) {
    (void)in_sizes; (void)n_in; (void)out_size; (void)ws_size;
    const int*   nodes     = (const int*)d_in[0];
    const int*   hist_ui   = (const int*)d_in[1];
    const int*   hist_r    = (const int*)d_in[2];
    const float* i2e_w     = (const float*)d_in[3];
    const float* u2e_w     = (const float*)d_in[4];
    const float* r2e_w     = (const float*)d_in[5];
    // d_in[6..13]: attention-score MLP params -- dead code (entmax over a
    // size-1 axis == 1.0 identically; head-1 renorm of unit vectors is identity).
    const float* gate_w    = (const float*)d_in[14];
    const float* gate_b    = (const float*)d_in[15];
    const float* gate1_w   = (const float*)d_in[16];
    const float* gate1_b   = (const float*)d_in[17];
    const float* bn_g      = (const float*)d_in[18];
    const float* bn_b      = (const float*)d_in[19];
    const float* inproj_w  = (const float*)d_in[20];
    const float* inproj_b  = (const float*)d_in[21];
    const float* bn1_g     = (const float*)d_in[22];
    const float* bn1_b     = (const float*)d_in[23];
    const float* outproj_w = (const float*)d_in[24];
    const float* outproj_b = (const float*)d_in[25];

    float* out = (float*)d_out;
    float* ws  = (float*)d_ws;
    float* ws_att = ws;                              // 262144
    float* ws_h1  = ws + 262144;                     // 262144
    float* cbuf   = ws + 524288;                     // 384
    unsigned short* wfrag  = (unsigned short*)(ws + 524672);  // 16 KB
    unsigned short* ipf_hi = (unsigned short*)(ws + 528768);  // 8 KB
    unsigned short* ipf_lo = (unsigned short*)(ws + 530816);  // 8 KB
    unsigned short* opf_hi = (unsigned short*)(ws + 532864);  // 8 KB
    unsigned short* opf_lo = (unsigned short*)(ws + 534912);  // 8 KB
    unsigned short* g1f    = (unsigned short*)(ws + 536960);  // 24 KB
    float* partials1 = ws + 543104;                  // 32*128
    float* partials2 = ws + 547200;                  // 64*128

    pk_all<<<8, 256, 0, stream>>>(gate_w, gate_b, r2e_w, inproj_w, outproj_w, gate1_w,
                                  wfrag, cbuf, ipf_hi, ipf_lo, opf_hi, opf_lo, g1f);
    k1_fuse<<<B_, 256, 0, stream>>>(hist_ui, hist_r, i2e_w, wfrag, cbuf, r2e_w, ws_att);
    k_statsP<<<32, 256, 0, stream>>>(ws_att, partials1);
    k_inproj<<<64, 256, 0, stream>>>(ws_att, partials1, bn_g, bn_b, ipf_hi, ipf_lo,
                                     inproj_b, ws_h1, partials2);
    k_final<<<64, 256, 0, stream>>>(ws_h1, partials2, bn1_g, bn1_b, opf_hi, opf_lo,
                                    outproj_b, nodes, u2e_w, g1f, gate1_b, out);
}